// Round 9
// baseline (305.326 us; speedup 1.0000x reference)
//
#include <hip/hip_runtime.h>
#include <hip/hip_bf16.h>
#include <math.h>

#define B_ 2
#define T_ 2048
#define C_ 2048
#define H_ 16
#define KVH_ 4
#define HD_ 128
#define G_ (H_ / KVH_)
#define MROWS (B_ * T_)                    // 4096
#define NQKV (H_ * HD_ + 2 * KVH_ * HD_)   // 3072
#define KOFF (H_ * HD_)                    // 2048
#define VOFF (H_ * HD_ + KVH_ * HD_)       // 2560
#define L2T (13.287712379549449f / 64.0f)  // log2(10000)/64

typedef __hip_bfloat16 bf16;
typedef short bf16x8 __attribute__((ext_vector_type(8)));   // 8 bf16 = 4 VGPR
typedef short bf16x4 __attribute__((ext_vector_type(4)));   // 4 bf16 = 2 VGPR
typedef float f32x4 __attribute__((ext_vector_type(4)));

__device__ __forceinline__ void gload_lds16(const void* g, void* l) {
  __builtin_amdgcn_global_load_lds(
      (const __attribute__((address_space(1))) unsigned int*)g,
      (__attribute__((address_space(3))) unsigned int*)l, 16, 0, 0);
}

static __device__ __forceinline__ f32x4 mfma32k(bf16x8 a, bf16x8 b, f32x4 c) {
  return __builtin_amdgcn_mfma_f32_16x16x32_bf16(a, b, c, 0, 0, 0);
}

// fast RNE f32->bf16 (no NaN handling; inputs are finite)
static __device__ __forceinline__ short f2bf(float x) {
  unsigned u = __builtin_bit_cast(unsigned, x);
  u += 0x7FFFu + ((u >> 16) & 1u);
  return (short)(u >> 16);
}

// bf16 (raw short) -> f32
static __device__ __forceinline__ float bfh2f(short h) {
  unsigned u = ((unsigned)(unsigned short)h) << 16;
  return __builtin_bit_cast(float, u);
}

static __device__ __forceinline__ float fexp2(float x) {
#if __has_builtin(__builtin_amdgcn_exp2f)
  return __builtin_amdgcn_exp2f(x);
#else
  return exp2f(x);
#endif
}

// ---------------------------------------------------------------------------
// Fused prep: [0,8192)   cast x fp32->bf16
//             [8192,14336)  wq|wk|wv transpose-cast -> wqkvT [3072][2048]
//             [14336,18432) wo transpose-cast -> woT [2048][2048]
//             [18432,18944) RoPE cos/sin table [2048][64] float2
// ---------------------------------------------------------------------------
__global__ __launch_bounds__(256) void prep_kernel(
    const float* __restrict__ x, bf16* __restrict__ xb,
    const float* __restrict__ wq, const float* __restrict__ wk,
    const float* __restrict__ wv, bf16* __restrict__ wqkvT,
    const float* __restrict__ wo, bf16* __restrict__ woT,
    float2* __restrict__ tab) {
  __shared__ float t[32][33];
  int bid = blockIdx.x;
  if (bid < 8192) {                        // ---- cast x
    const int i = (bid * 256 + threadIdx.x) * 4;
    float4 v = *(const float4*)(x + i);
    xb[i + 0] = __float2bfloat16(v.x);
    xb[i + 1] = __float2bfloat16(v.y);
    xb[i + 2] = __float2bfloat16(v.z);
    xb[i + 3] = __float2bfloat16(v.w);
    return;
  }
  bid -= 8192;
  if (bid < 6144) {                        // ---- qkv weight transpose
    const int tx = threadIdx.x & 31, ty = threadIdx.x >> 5;
    const int c0 = (bid % 96) * 32;        // fused n-dim 0..3071
    const int r0 = (bid / 96) * 32;        // k-dim
    const float* src;
    int nn, ld;
    if (c0 < KOFF)      { src = wq; nn = c0;        ld = 2048; }
    else if (c0 < VOFF) { src = wk; nn = c0 - KOFF; ld = 512; }
    else                { src = wv; nn = c0 - VOFF; ld = 512; }
#pragma unroll
    for (int it = 0; it < 4; ++it)
      t[ty + 8 * it][tx] = src[(size_t)(r0 + ty + 8 * it) * ld + nn + tx];
    __syncthreads();
#pragma unroll
    for (int it = 0; it < 4; ++it)
      wqkvT[(size_t)(c0 + ty + 8 * it) * 2048 + r0 + tx] =
          __float2bfloat16(t[tx][ty + 8 * it]);
    return;
  }
  bid -= 6144;
  if (bid < 4096) {                        // ---- wo transpose
    const int tx = threadIdx.x & 31, ty = threadIdx.x >> 5;
    const int c0 = (bid & 63) * 32;
    const int r0 = (bid >> 6) * 32;
#pragma unroll
    for (int it = 0; it < 4; ++it)
      t[ty + 8 * it][tx] = wo[(size_t)(r0 + ty + 8 * it) * 2048 + c0 + tx];
    __syncthreads();
#pragma unroll
    for (int it = 0; it < 4; ++it)
      woT[(size_t)(c0 + ty + 8 * it) * 2048 + r0 + tx] =
          __float2bfloat16(t[tx][ty + 8 * it]);
    return;
  }
  bid -= 4096;
  {                                        // ---- RoPE table
    const int idx = bid * 256 + threadIdx.x;   // [0, 131072)
    const int tt = idx >> 6, i = idx & 63;
    const float invf = fexp2(-(float)i * L2T);
    float s, c;
    __sincosf((float)tt * invf, &s, &c);
    tab[idx] = make_float2(c, s);
  }
}

// ---------------------------------------------------------------------------
// bf16 MFMA GEMM, m97 loop structure with BK=64 + XOR swizzle (r7), plus
// FUSED K/V rope+pack epilogue (r8) for the QKV projection.
// Main loop identical to r7 (verified): 128x128 tile, 4 waves, BK=64,
// 2 barriers/tile; LDS rows 128B with 16B-slot XOR swizzle row&7 on both
// sides (pre-swizzled gload source / swizzled ds_read).
// FUSE epilogue (QKV only, blocks with c0 >= KOFF): the 128x128 output tile
// is exactly one kv head x 4 kv-tiles (blocks are head-aligned). Instead of
// writing qkv rows + a separate pack_kv dispatch:
//   1) sync; dump bias-added acc as bf16 into the (dead) 32KB staging LDS as
//      T[128][128], col XOR-swizzled with (row&7)<<3 (8-aligned groups map to
//      8-aligned groups -> 16B read contiguity preserved; K-read conflict
//      16-way -> 4-way);
//   2) barrier; each thread emits 8 x 16B units in the r4-verified kp/vp
//      fragment-major layouts; K gets table-RoPE in f32 (single rounding).
// Q blocks (c0 < KOFF) write qkv rows as before (flash reads only Q cols).
// ---------------------------------------------------------------------------
template <bool BF16OUT, bool FUSE>
__global__ __launch_bounds__(256, 2) void gemm_mfma64(
    const bf16* __restrict__ A, const bf16* __restrict__ Bt, void* __restrict__ Cout,
    const float* __restrict__ bq, const float* __restrict__ bk2,
    const float* __restrict__ bv2, int M, int N, int K,
    bf16* __restrict__ kp, bf16* __restrict__ vp, const float2* __restrict__ tab) {
  __shared__ __align__(16) short SH[2 * 128 * 64];  // As | Bs; FUSE: C-tile 128x128
  short* As = SH;
  short* Bs = SH + 128 * 64;
  const int tid = threadIdx.x;
  const int w = tid >> 6, lane = tid & 63;
  const int colL = lane & 15, quad = lane >> 4;
  const int wm = w & 1, wn = w >> 1;
  const int r0 = blockIdx.y * 128, c0 = blockIdx.x * 128;
  const int lrow = lane >> 3;                 // src row within 8-row seg
  const int lsl = ((lane & 7) ^ lrow) * 8;    // pre-swizzled src k-elems
  const int c7 = colL & 7;
  const int sq0 = (quad ^ c7) * 8;            // read slot (elems), ks=0
  const int sq1 = ((4 + quad) ^ c7) * 8;      // ks=1

  f32x4 acc[4][4];
  const f32x4 zero = {0.f, 0.f, 0.f, 0.f};
#pragma unroll
  for (int mt = 0; mt < 4; ++mt)
#pragma unroll
    for (int nt = 0; nt < 4; ++nt) acc[mt][nt] = zero;

  const bf16* pa = A + (size_t)(r0 + lrow) * K + lsl;
  const bf16* pb = Bt + (size_t)(c0 + lrow) * K + lsl;

  for (int k0 = 0; k0 < K; k0 += 64) {
    __syncthreads();                       // WAR: prev reads done (drains vmcnt too)
#pragma unroll
    for (int it = 0; it < 4; ++it) {
      const int seg = it * 4 + w;          // 16 segs x 8 rows x 128B
      gload_lds16(pa + (size_t)seg * 8 * K + k0, &As[seg * 8 * 64]);
      gload_lds16(pb + (size_t)seg * 8 * K + k0, &Bs[seg * 8 * 64]);
    }
    __syncthreads();                       // RAW: staging complete
#pragma unroll
    for (int ks = 0; ks < 2; ++ks) {
      const int sq = ks ? sq1 : sq0;
      bf16x8 af[4], bfv[4];
#pragma unroll
      for (int mt = 0; mt < 4; ++mt)
        af[mt] = *(const bf16x8*)&As[(wm * 64 + mt * 16 + colL) * 64 + sq];
#pragma unroll
      for (int nt = 0; nt < 4; ++nt)
        bfv[nt] = *(const bf16x8*)&Bs[(wn * 64 + nt * 16 + colL) * 64 + sq];
#pragma unroll
      for (int mt = 0; mt < 4; ++mt)
#pragma unroll
        for (int nt = 0; nt < 4; ++nt)
          acc[mt][nt] = mfma32k(af[mt], bfv[nt], acc[mt][nt]);
    }
  }

  if (!FUSE || c0 < KOFF) {
    // ---- plain epilogue: (bias +) store to Cout
#pragma unroll
    for (int nt = 0; nt < 4; ++nt) {
      const int c = c0 + wn * 64 + nt * 16 + colL;
      float bias = 0.f;
      if (bq) bias = (c < KOFF) ? bq[c] : (c < VOFF ? bk2[c - KOFF] : bv2[c - VOFF]);
#pragma unroll
      for (int mt = 0; mt < 4; ++mt) {
#pragma unroll
        for (int i = 0; i < 4; ++i) {
          const int r = r0 + wm * 64 + mt * 16 + quad * 4 + i;
          const float v = acc[mt][nt][i] + bias;
          if (BF16OUT)
            ((bf16*)Cout)[(size_t)r * N + c] = __float2bfloat16(v);
          else
            ((float*)Cout)[(size_t)r * N + c] = v;
        }
      }
    }
  } else {
    // ---- fused K/V rope+pack epilogue
    __syncthreads();                       // all As/Bs fragment reads complete
    const bool isK = (c0 < VOFF);
#pragma unroll
    for (int nt = 0; nt < 4; ++nt) {
      const int c = c0 + wn * 64 + nt * 16 + colL;
      const float bias = isK ? bk2[c - KOFF] : bv2[c - VOFF];
      const int col = wn * 64 + nt * 16 + colL;
#pragma unroll
      for (int mt = 0; mt < 4; ++mt) {
#pragma unroll
        for (int i = 0; i < 4; ++i) {
          const int row = wm * 64 + mt * 16 + quad * 4 + i;
          SH[row * 128 + (col ^ ((row & 7) << 3))] = f2bf(acc[mt][nt][i] + bias);
        }
      }
    }
    __syncthreads();
    const int b = r0 >> 11;                         // batch
    const int tbase = (r0 & 2047) >> 5;             // first 32-row kv tile
    const int kvh = (c0 - (isK ? KOFF : VOFF)) >> 7;
    const int bkq = b * 4 + kvh;
    if (isK) {
#pragma unroll
      for (int s = 0; s < 8; ++s) {
        const int unit = s * 256 + tid;             // 2048 16B-units
        const int L = unit & 63, kc = (unit >> 6) & 7, tile = unit >> 9;
        const int trow = tile * 32 + ((L >> 2) & 3) * 8 + ((kc >> 2) << 2) + (L & 3);
        const int d = (kc & 3) * 32 + ((L >> 4) << 3);
        const int sx = (trow & 7) << 3;
        bf16x8 lo = *(const bf16x8*)&SH[trow * 128 + (d ^ sx)];
        bf16x8 hi = *(const bf16x8*)&SH[trow * 128 + ((d ^ 64) ^ sx)];
        const int t_abs = (r0 + trow) & (T_ - 1);
        const float2* tp = tab + t_abs * 64 + (d & 63);
        bf16x8 outv;
#pragma unroll
        for (int j = 0; j < 8; ++j) {
          const float2 cs = tp[j];
          const float a = bfh2f(lo[j]), p = bfh2f(hi[j]);
          outv[j] = f2bf((d < 64) ? (a * cs.x - p * cs.y) : (a * cs.x + p * cs.y));
        }
        *(bf16x8*)(kp + ((size_t)((bkq * 64 + tbase + tile) * 8 + kc)) * 512 + L * 8) = outv;
      }
    } else {
#pragma unroll
      for (int s = 0; s < 8; ++s) {
        const int unit = s * 256 + tid;
        const int L = unit & 63, ht = (unit >> 6) & 7, tile = unit >> 9;
        const int rowb = tile * 32 + ((L >> 4) << 3);
        const int colv = ht * 16 + (L & 15);
        bf16x8 v;
#pragma unroll
        for (int j = 0; j < 8; ++j)
          v[j] = SH[(rowb + j) * 128 + (colv ^ (((rowb + j) & 7) << 3))];
        *(bf16x8*)(vp + ((size_t)((bkq * 64 + tbase + tile) * 8 + ht)) * 512 + L * 8) = v;
      }
    }
  }
}

// ---------------------------------------------------------------------------
// Causal GQA flash attention v14: v12 + V in REGISTERS (T14 async-stage).
// V never touches LDS: each wave consumed the whole 8KB V tile as fragments
// anyway, so LDS-staging only coupled the V L2-round-trip to the block-wide
// barrier (the measured per-iter convoy stall). Now V(tt) is loaded
// global->reg (8 x b128, 32 VGPR) at iteration top; qk+softmax (~250 issue
// cycles) hide the L2 hit; the compiler's auto-waitcnt before PV is a
// per-wave counted wait (vmcnt(2): only K(tt+3)'s 2 gload_lds are newer).
// End-of-iter barrier carries NO vmcnt: K(tt+2) (issued last iter) is
// FIFO-drained by the pre-PV wait. K stays LDS-shared (3x8KB, distance 3).
// LDS 40->24KB, launch_bounds(256,5): 5 blocks/CU = 20 waves (was 16).
// Everything else = v12/r6 config (measured best): 16-row q-tiles, 1024
// blocks, jq=127-u, in-register Q RoPE, PV single K=32 MFMA per ht,
// fixed-max softmax (exact).
// ---------------------------------------------------------------------------
#define FA_SCL2 (0.08838834764831845f * 1.4426950408889634f)  // scale * log2(e)
#define FA_M2 16.0f                                           // fixed max (exp2 domain)

__global__ __launch_bounds__(256, 5) void flash_mfma8(
    const bf16* __restrict__ qkv, const bf16* __restrict__ kp,
    const bf16* __restrict__ vp, bf16* __restrict__ ao,
    const float2* __restrict__ tab) {
  __shared__ __align__(16) bf16 KS[3][4096];   // 3 x 8KB (V is reg-staged)

  const int id = blockIdx.x;
  const int bk = id & 7;                   // b*KVH + kvh  (== XCD id under %8 rr)
  const int u = id >> 3;                   // 0..127
  const int jq = 127 - u;                  // descending work order
  const int b = bk >> 2, kvh = bk & 3;
  const int w = threadIdx.x >> 6;          // wave = q-head within group
  const int h = (kvh << 2) | w;
  const int lane = threadIdx.x & 63;
  const int colL = lane & 15, quad = lane >> 4;
  const int myq0 = jq * 16;                // 16 q-rows per block
  const int nkv = (jq >> 1) + 1;           // 32-row kv tiles covering causal range

  const bf16* kpt = kp + ((size_t)(bk * 64)) * 4096 + (w * 2) * 512 + lane * 8;
  const bf16* vbase = vp + ((size_t)(bk * 64)) * 4096 + lane * 8;

  auto stageK = [&](int tile, int slot) {
    const bf16* s = kpt + (size_t)tile * 4096;
    bf16* d = &KS[slot][(w * 2) * 512];    // wave-uniform base; HW adds lane*16B
    gload_lds16(s, d);
    gload_lds16(s + 512, d + 512);
  };

  // Q fragments (B-operand of K·Q^T), RoPE'd in registers.
  bf16x8 qf[4];
  {
    const bf16* qg = qkv + (size_t)(b * T_ + myq0) * NQKV + h * HD_;
    bf16x8 rq[4];
#pragma unroll
    for (int c = 0; c < 4; ++c)
      rq[c] = *(const bf16x8*)(qg + (size_t)colL * NQKV + c * 32 + quad * 8);
    const float2* tp = tab + (myq0 + colL) * 64 + quad * 8;
    float2 cs0[8], cs1[8];
#pragma unroll
    for (int jj = 0; jj < 8; ++jj) { cs0[jj] = tp[jj]; cs1[jj] = tp[32 + jj]; }
#pragma unroll
    for (int c = 0; c < 4; ++c) {
#pragma unroll
      for (int jj = 0; jj < 8; ++jj) {
        const float2 cs = (c & 1) ? cs1[jj] : cs0[jj];
        const float a = bfh2f(rq[c][jj]), p = bfh2f(rq[c ^ 2][jj]);
        qf[c][jj] = f2bf((c & 2) ? (a * cs.x + p * cs.y)
                                 : (a * cs.x - p * cs.y));
      }
    }
  }

  const f32x4 zero = {0.f, 0.f, 0.f, 0.f};
  auto qk = [&](const bf16* Kb, f32x4 (&s_)[2]) {
    s_[0] = zero; s_[1] = zero;
#pragma unroll
    for (int c = 0; c < 4; ++c) {
      bf16x8 kf0 = *(const bf16x8*)(Kb + c * 512 + lane * 8);
      bf16x8 kf1 = *(const bf16x8*)(Kb + (4 + c) * 512 + lane * 8);
      s_[0] = mfma32k(kf0, qf[c], s_[0]);
      s_[1] = mfma32k(kf1, qf[c], s_[1]);
    }
  };

  f32x4 o[8];
#pragma unroll
  for (int ht = 0; ht < 8; ++ht) o[ht] = zero;
  float l_ = 0.f;

  // prologue: K tiles 0..2 into LDS; full drain; QK(0)
  stageK(0, 0);
  if (nkv > 1) stageK(1, 1);
  if (nkv > 2) stageK(2, 2);
  asm volatile("s_waitcnt vmcnt(0)\n\ts_barrier" ::: "memory");

  f32x4 sA[2], sB[2];
  qk(KS[0], sA);

  int kStage = 0, kNext = 1;
#pragma unroll 1
  for (int tt = 0; tt < nkv; ++tt) {
    const bool sk = (tt + 3 < nkv);

    // V(tt) global->reg: issued first, consumed after qk+softmax (T14 split;
    // compiler inserts the counted vmcnt before first use = before PV)
    bf16x8 vr[8];
    {
      const bf16* vsrc = vbase + (size_t)tt * 4096;
#pragma unroll
      for (int ht = 0; ht < 8; ++ht)
        vr[ht] = *(const bf16x8*)(vsrc + ht * 512);
    }
    if (sk) stageK(tt + 3, kStage);        // overwrites K(tt) slot: dead since iter tt-1

    // QK(t+1): MFMA pipe busy while VALU does softmax(t)
    if (tt + 1 < nkv) qk(KS[kNext], sB);

    // softmax on sA (tile tt); key-in-frame = quad*8 + kt*4 + i (r4 mapping)
    bf16x4 pf[2];
    if (tt == nkv - 1) {
      const int qg = ((jq & 1) << 4) | colL;   // q offset within 32-row kv frame
#pragma unroll
      for (int kt = 0; kt < 2; ++kt) {
        const int kb = quad * 8 + kt * 4;
        float pv[4];
#pragma unroll
        for (int i = 0; i < 4; ++i) {
          float e = fexp2(fmaf(sA[kt][i], FA_SCL2, -FA_M2));
          pv[i] = (kb + i <= qg) ? e : 0.f;
        }
        l_ += (pv[0] + pv[1]) + (pv[2] + pv[3]);
        pf[kt] = (bf16x4){f2bf(pv[0]), f2bf(pv[1]), f2bf(pv[2]), f2bf(pv[3])};
      }
    } else {
#pragma unroll
      for (int kt = 0; kt < 2; ++kt) {
        float pv[4];
#pragma unroll
        for (int i = 0; i < 4; ++i)
          pv[i] = fexp2(fmaf(sA[kt][i], FA_SCL2, -FA_M2));
        l_ += (pv[0] + pv[1]) + (pv[2] + pv[3]);
        pf[kt] = (bf16x4){f2bf(pv[0]), f2bf(pv[1]), f2bf(pv[2]), f2bf(pv[3])};
      }
    }

    // PV(tt): O^T += V^T · P^T — single K=32 MFMA per ht, V from registers
    {
      const bf16x8 pcat = __builtin_shufflevector(pf[0], pf[1], 0, 1, 2, 3, 4, 5, 6, 7);
#pragma unroll
      for (int ht = 0; ht < 8; ++ht)
        o[ht] = mfma32k(vr[ht], pcat, o[ht]);
    }

    // K-slot publish/WAR barrier only; K(tt+2) already FIFO-drained by the
    // compiler's pre-PV V-wait (vmcnt counts gload_lds too)
    __builtin_amdgcn_s_barrier();

    sA[0] = sB[0]; sA[1] = sB[1];
    kStage = (kStage == 2) ? 0 : kStage + 1;
    kNext  = (kNext == 2) ? 0 : kNext + 1;
  }

  // epilogue: reduce l over key-quads, scale, direct store
  {
    float lv = l_;
    lv += __shfl_xor(lv, 16);
    lv += __shfl_xor(lv, 32);
    const float rl = 1.f / lv;
    const size_t rbase = (size_t)(b * T_ + myq0 + colL) * (H_ * HD_) + h * HD_;
#pragma unroll
    for (int ht = 0; ht < 8; ++ht) {
      bf16x4 ov;
#pragma unroll
      for (int i = 0; i < 4; ++i) ov[i] = f2bf(o[ht][i] * rl);
      *(bf16x4*)(ao + rbase + ht * 16 + quad * 4) = ov;
    }
  }
}

// ---------------------------------------------------------------------------
extern "C" void kernel_launch(void* const* d_in, const int* in_sizes, int n_in,
                              void* d_out, int out_size, void* d_ws, size_t ws_size,
                              hipStream_t stream) {
  (void)in_sizes; (void)n_in; (void)out_size; (void)ws_size;
  const float* x  = (const float*)d_in[0];
  const float* wq = (const float*)d_in[1];
  const float* bq = (const float*)d_in[2];
  const float* wk = (const float*)d_in[3];
  const float* bk = (const float*)d_in[4];
  const float* wv = (const float*)d_in[5];
  const float* bv = (const float*)d_in[6];
  const float* wo = (const float*)d_in[7];
  float* out = (float*)d_out;

  char* ws = (char*)d_ws;
  bf16* xb    = (bf16*)ws;                 // 16 MiB; reused as ao after QKV gemm
  bf16* wqkvT = (bf16*)(ws + (16u << 20)); // 12 MiB [3072][2048]
  bf16* woT   = (bf16*)(ws + (28u << 20)); //  8 MiB [2048][2048]
  bf16* qkv   = (bf16*)(ws + (36u << 20)); // 24 MiB [4096][3072] (Q cols only)
  bf16* kp    = (bf16*)(ws + (60u << 20)); //  8 MiB fragment-major roped K'
  bf16* vp    = (bf16*)(ws + (68u << 20)); //  8 MiB fragment-major V'
  float2* tab = (float2*)(ws + (76u << 20)); // 1 MiB RoPE cos/sin [2048][64]

  // 1: all independent prep (cast, weight transposes, rope table)
  prep_kernel<<<dim3(18944), dim3(256), 0, stream>>>(
      x, xb, wq, wk, wv, wqkvT, wo, woT, tab);

  // 2: fused QKV projection + K rope+pack / V pack in epilogue
  gemm_mfma64<true, true><<<dim3(NQKV / 128, MROWS / 128), dim3(256), 0, stream>>>(
      xb, wqkvT, qkv, bq, bk, bv, MROWS, NQKV, C_, kp, vp, tab);

  // 3: flash attention (Q roped in registers, V reg-staged, 5 blocks/CU)
  bf16* ao = xb;
  flash_mfma8<<<dim3(1024), dim3(256), 0, stream>>>(qkv, kp, vp, ao, tab);

  // 4: output projection (m97 structure, BK=64 + swizzle)
  gemm_mfma64<false, false><<<dim3(C_ / 128, MROWS / 128), dim3(256), 0, stream>>>(
      ao, woT, out, nullptr, nullptr, nullptr, MROWS, C_, KOFF,
      nullptr, nullptr, nullptr);
}

// Round 10
// 293.226 us; speedup vs baseline: 1.0413x; 1.0413x over previous
//
#include <hip/hip_runtime.h>
#include <hip/hip_bf16.h>
#include <math.h>

#define B_ 2
#define T_ 2048
#define C_ 2048
#define H_ 16
#define KVH_ 4
#define HD_ 128
#define G_ (H_ / KVH_)
#define MROWS (B_ * T_)                    // 4096
#define NQKV (H_ * HD_ + 2 * KVH_ * HD_)   // 3072
#define KOFF (H_ * HD_)                    // 2048
#define VOFF (H_ * HD_ + KVH_ * HD_)       // 2560
#define L2T (13.287712379549449f / 64.0f)  // log2(10000)/64

typedef __hip_bfloat16 bf16;
typedef short bf16x8 __attribute__((ext_vector_type(8)));   // 8 bf16 = 4 VGPR
typedef short bf16x4 __attribute__((ext_vector_type(4)));   // 4 bf16 = 2 VGPR
typedef float f32x4 __attribute__((ext_vector_type(4)));

__device__ __forceinline__ void gload_lds16(const void* g, void* l) {
  __builtin_amdgcn_global_load_lds(
      (const __attribute__((address_space(1))) unsigned int*)g,
      (__attribute__((address_space(3))) unsigned int*)l, 16, 0, 0);
}

static __device__ __forceinline__ f32x4 mfma32k(bf16x8 a, bf16x8 b, f32x4 c) {
  return __builtin_amdgcn_mfma_f32_16x16x32_bf16(a, b, c, 0, 0, 0);
}

// fast RNE f32->bf16 (no NaN handling; inputs are finite)
static __device__ __forceinline__ short f2bf(float x) {
  unsigned u = __builtin_bit_cast(unsigned, x);
  u += 0x7FFFu + ((u >> 16) & 1u);
  return (short)(u >> 16);
}

// bf16 (raw short) -> f32
static __device__ __forceinline__ float bfh2f(short h) {
  unsigned u = ((unsigned)(unsigned short)h) << 16;
  return __builtin_bit_cast(float, u);
}

static __device__ __forceinline__ float fexp2(float x) {
#if __has_builtin(__builtin_amdgcn_exp2f)
  return __builtin_amdgcn_exp2f(x);
#else
  return exp2f(x);
#endif
}

// ---------------------------------------------------------------------------
// Fused prep: [0,8192)   cast x fp32->bf16
//             [8192,14336)  wq|wk|wv transpose-cast -> wqkvT [3072][2048]
//             [14336,18432) wo transpose-cast -> woT [2048][2048]
//             [18432,18944) RoPE cos/sin table [2048][64] float2
// ---------------------------------------------------------------------------
__global__ __launch_bounds__(256) void prep_kernel(
    const float* __restrict__ x, bf16* __restrict__ xb,
    const float* __restrict__ wq, const float* __restrict__ wk,
    const float* __restrict__ wv, bf16* __restrict__ wqkvT,
    const float* __restrict__ wo, bf16* __restrict__ woT,
    float2* __restrict__ tab) {
  __shared__ float t[32][33];
  int bid = blockIdx.x;
  if (bid < 8192) {                        // ---- cast x
    const int i = (bid * 256 + threadIdx.x) * 4;
    float4 v = *(const float4*)(x + i);
    xb[i + 0] = __float2bfloat16(v.x);
    xb[i + 1] = __float2bfloat16(v.y);
    xb[i + 2] = __float2bfloat16(v.z);
    xb[i + 3] = __float2bfloat16(v.w);
    return;
  }
  bid -= 8192;
  if (bid < 6144) {                        // ---- qkv weight transpose
    const int tx = threadIdx.x & 31, ty = threadIdx.x >> 5;
    const int c0 = (bid % 96) * 32;        // fused n-dim 0..3071
    const int r0 = (bid / 96) * 32;        // k-dim
    const float* src;
    int nn, ld;
    if (c0 < KOFF)      { src = wq; nn = c0;        ld = 2048; }
    else if (c0 < VOFF) { src = wk; nn = c0 - KOFF; ld = 512; }
    else                { src = wv; nn = c0 - VOFF; ld = 512; }
#pragma unroll
    for (int it = 0; it < 4; ++it)
      t[ty + 8 * it][tx] = src[(size_t)(r0 + ty + 8 * it) * ld + nn + tx];
    __syncthreads();
#pragma unroll
    for (int it = 0; it < 4; ++it)
      wqkvT[(size_t)(c0 + ty + 8 * it) * 2048 + r0 + tx] =
          __float2bfloat16(t[tx][ty + 8 * it]);
    return;
  }
  bid -= 6144;
  if (bid < 4096) {                        // ---- wo transpose
    const int tx = threadIdx.x & 31, ty = threadIdx.x >> 5;
    const int c0 = (bid & 63) * 32;
    const int r0 = (bid >> 6) * 32;
#pragma unroll
    for (int it = 0; it < 4; ++it)
      t[ty + 8 * it][tx] = wo[(size_t)(r0 + ty + 8 * it) * 2048 + c0 + tx];
    __syncthreads();
#pragma unroll
    for (int it = 0; it < 4; ++it)
      woT[(size_t)(c0 + ty + 8 * it) * 2048 + r0 + tx] =
          __float2bfloat16(t[tx][ty + 8 * it]);
    return;
  }
  bid -= 4096;
  {                                        // ---- RoPE table
    const int idx = bid * 256 + threadIdx.x;   // [0, 131072)
    const int tt = idx >> 6, i = idx & 63;
    const float invf = fexp2(-(float)i * L2T);
    float s, c;
    __sincosf((float)tt * invf, &s, &c);
    tab[idx] = make_float2(c, s);
  }
}

// ---------------------------------------------------------------------------
// bf16 MFMA GEMM, m97 loop structure with BK=64 + XOR swizzle (r7), plus
// FUSED K/V rope+pack epilogue (r8) for the QKV projection.
// Main loop identical to r7 (verified): 128x128 tile, 4 waves, BK=64,
// 2 barriers/tile; LDS rows 128B with 16B-slot XOR swizzle row&7 on both
// sides (pre-swizzled gload source / swizzled ds_read).
// FUSE epilogue (QKV only, blocks with c0 >= KOFF): the 128x128 output tile
// is exactly one kv head x 4 kv-tiles (blocks are head-aligned). Instead of
// writing qkv rows + a separate pack_kv dispatch:
//   1) sync; dump bias-added acc as bf16 into the (dead) 32KB staging LDS as
//      T[128][128], col XOR-swizzled with (row&7)<<3 (8-aligned groups map to
//      8-aligned groups -> 16B read contiguity preserved; K-read conflict
//      16-way -> 4-way);
//   2) barrier; each thread emits 8 x 16B units in the r4-verified kp/vp
//      fragment-major layouts; K gets table-RoPE in f32 (single rounding).
// Q blocks (c0 < KOFF) write qkv rows as before (flash reads only Q cols).
// ---------------------------------------------------------------------------
template <bool BF16OUT, bool FUSE>
__global__ __launch_bounds__(256, 2) void gemm_mfma64(
    const bf16* __restrict__ A, const bf16* __restrict__ Bt, void* __restrict__ Cout,
    const float* __restrict__ bq, const float* __restrict__ bk2,
    const float* __restrict__ bv2, int M, int N, int K,
    bf16* __restrict__ kp, bf16* __restrict__ vp, const float2* __restrict__ tab) {
  __shared__ __align__(16) short SH[2 * 128 * 64];  // As | Bs; FUSE: C-tile 128x128
  short* As = SH;
  short* Bs = SH + 128 * 64;
  const int tid = threadIdx.x;
  const int w = tid >> 6, lane = tid & 63;
  const int colL = lane & 15, quad = lane >> 4;
  const int wm = w & 1, wn = w >> 1;
  const int r0 = blockIdx.y * 128, c0 = blockIdx.x * 128;
  const int lrow = lane >> 3;                 // src row within 8-row seg
  const int lsl = ((lane & 7) ^ lrow) * 8;    // pre-swizzled src k-elems
  const int c7 = colL & 7;
  const int sq0 = (quad ^ c7) * 8;            // read slot (elems), ks=0
  const int sq1 = ((4 + quad) ^ c7) * 8;      // ks=1

  f32x4 acc[4][4];
  const f32x4 zero = {0.f, 0.f, 0.f, 0.f};
#pragma unroll
  for (int mt = 0; mt < 4; ++mt)
#pragma unroll
    for (int nt = 0; nt < 4; ++nt) acc[mt][nt] = zero;

  const bf16* pa = A + (size_t)(r0 + lrow) * K + lsl;
  const bf16* pb = Bt + (size_t)(c0 + lrow) * K + lsl;

  for (int k0 = 0; k0 < K; k0 += 64) {
    __syncthreads();                       // WAR: prev reads done (drains vmcnt too)
#pragma unroll
    for (int it = 0; it < 4; ++it) {
      const int seg = it * 4 + w;          // 16 segs x 8 rows x 128B
      gload_lds16(pa + (size_t)seg * 8 * K + k0, &As[seg * 8 * 64]);
      gload_lds16(pb + (size_t)seg * 8 * K + k0, &Bs[seg * 8 * 64]);
    }
    __syncthreads();                       // RAW: staging complete
#pragma unroll
    for (int ks = 0; ks < 2; ++ks) {
      const int sq = ks ? sq1 : sq0;
      bf16x8 af[4], bfv[4];
#pragma unroll
      for (int mt = 0; mt < 4; ++mt)
        af[mt] = *(const bf16x8*)&As[(wm * 64 + mt * 16 + colL) * 64 + sq];
#pragma unroll
      for (int nt = 0; nt < 4; ++nt)
        bfv[nt] = *(const bf16x8*)&Bs[(wn * 64 + nt * 16 + colL) * 64 + sq];
#pragma unroll
      for (int mt = 0; mt < 4; ++mt)
#pragma unroll
        for (int nt = 0; nt < 4; ++nt)
          acc[mt][nt] = mfma32k(af[mt], bfv[nt], acc[mt][nt]);
    }
  }

  if (!FUSE || c0 < KOFF) {
    // ---- plain epilogue: (bias +) store to Cout
#pragma unroll
    for (int nt = 0; nt < 4; ++nt) {
      const int c = c0 + wn * 64 + nt * 16 + colL;
      float bias = 0.f;
      if (bq) bias = (c < KOFF) ? bq[c] : (c < VOFF ? bk2[c - KOFF] : bv2[c - VOFF]);
#pragma unroll
      for (int mt = 0; mt < 4; ++mt) {
#pragma unroll
        for (int i = 0; i < 4; ++i) {
          const int r = r0 + wm * 64 + mt * 16 + quad * 4 + i;
          const float v = acc[mt][nt][i] + bias;
          if (BF16OUT)
            ((bf16*)Cout)[(size_t)r * N + c] = __float2bfloat16(v);
          else
            ((float*)Cout)[(size_t)r * N + c] = v;
        }
      }
    }
  } else {
    // ---- fused K/V rope+pack epilogue
    __syncthreads();                       // all As/Bs fragment reads complete
    const bool isK = (c0 < VOFF);
#pragma unroll
    for (int nt = 0; nt < 4; ++nt) {
      const int c = c0 + wn * 64 + nt * 16 + colL;
      const float bias = isK ? bk2[c - KOFF] : bv2[c - VOFF];
      const int col = wn * 64 + nt * 16 + colL;
#pragma unroll
      for (int mt = 0; mt < 4; ++mt) {
#pragma unroll
        for (int i = 0; i < 4; ++i) {
          const int row = wm * 64 + mt * 16 + quad * 4 + i;
          SH[row * 128 + (col ^ ((row & 7) << 3))] = f2bf(acc[mt][nt][i] + bias);
        }
      }
    }
    __syncthreads();
    const int b = r0 >> 11;                         // batch
    const int tbase = (r0 & 2047) >> 5;             // first 32-row kv tile
    const int kvh = (c0 - (isK ? KOFF : VOFF)) >> 7;
    const int bkq = b * 4 + kvh;
    if (isK) {
#pragma unroll
      for (int s = 0; s < 8; ++s) {
        const int unit = s * 256 + tid;             // 2048 16B-units
        const int L = unit & 63, kc = (unit >> 6) & 7, tile = unit >> 9;
        const int trow = tile * 32 + ((L >> 2) & 3) * 8 + ((kc >> 2) << 2) + (L & 3);
        const int d = (kc & 3) * 32 + ((L >> 4) << 3);
        const int sx = (trow & 7) << 3;
        bf16x8 lo = *(const bf16x8*)&SH[trow * 128 + (d ^ sx)];
        bf16x8 hi = *(const bf16x8*)&SH[trow * 128 + ((d ^ 64) ^ sx)];
        const int t_abs = (r0 + trow) & (T_ - 1);
        const float2* tp = tab + t_abs * 64 + (d & 63);
        bf16x8 outv;
#pragma unroll
        for (int j = 0; j < 8; ++j) {
          const float2 cs = tp[j];
          const float a = bfh2f(lo[j]), p = bfh2f(hi[j]);
          outv[j] = f2bf((d < 64) ? (a * cs.x - p * cs.y) : (a * cs.x + p * cs.y));
        }
        *(bf16x8*)(kp + ((size_t)((bkq * 64 + tbase + tile) * 8 + kc)) * 512 + L * 8) = outv;
      }
    } else {
#pragma unroll
      for (int s = 0; s < 8; ++s) {
        const int unit = s * 256 + tid;
        const int L = unit & 63, ht = (unit >> 6) & 7, tile = unit >> 9;
        const int rowb = tile * 32 + ((L >> 4) << 3);
        const int colv = ht * 16 + (L & 15);
        bf16x8 v;
#pragma unroll
        for (int j = 0; j < 8; ++j)
          v[j] = SH[(rowb + j) * 128 + (colv ^ (((rowb + j) & 7) << 3))];
        *(bf16x8*)(vp + ((size_t)((bkq * 64 + tbase + tile) * 8 + ht)) * 512 + L * 8) = v;
      }
    }
  }
}

// ---------------------------------------------------------------------------
// Causal GQA flash attention v16: r8 base (V via gload_lds — r9's reg-staged V
// REVERTED: compiler sank the loads, VGPR 48 proved vr wasn't live) with the
// prefetch ledger re-balanced so the end-of-iter wait covers only loads
// issued ONE FULL ITERATION earlier (no same-iteration L2 round-trip under
// the barrier):
//   K: 2 slots @ distance 2 (slot = tile&1); V: 3 slots @ distance 2
//   (slot = tile%3). LDS 2x8 + 3x8 = 40KB -> 4 blocks/CU (unchanged).
//   Iter tt issues stageV(tt+2), stageK(tt+2) [4 gloads];
//   end-of-iter vmcnt(4) drains K(tt+1),V(tt+1) (issued at tt-1; latency
//   already covered) and leaves this iter's 4 in flight. Tail: vmcnt(0).
//   FIFO-walked for nkv = 1,2,3, steady, tail.
// New barrier after prologue qk(KS[0]): closes the slot-0 WAR race (iter-0
// stageK(tile2 -> slot0) vs other waves' prologue reads of tile 0). All other
// slot overwrites are separated by end-of-iter barriers (tile t's slot is
// last read at iter t-1).
// Everything else = r6/r8 proven config: 16-row q-tiles, 1024 blocks,
// jq=127-u, in-register Q RoPE, PV single K=32 MFMA per ht, fixed-max
// softmax (exact).
// ---------------------------------------------------------------------------
#define FA_SCL2 (0.08838834764831845f * 1.4426950408889634f)  // scale * log2(e)
#define FA_M2 16.0f                                           // fixed max (exp2 domain)

__global__ __launch_bounds__(256, 4) void flash_mfma8(
    const bf16* __restrict__ qkv, const bf16* __restrict__ kp,
    const bf16* __restrict__ vp, bf16* __restrict__ ao,
    const float2* __restrict__ tab) {
  __shared__ __align__(16) bf16 KS[2][4096];   // 2 x 8KB, dist 2
  __shared__ __align__(16) bf16 VS[3][4096];   // 3 x 8KB, dist 2

  const int id = blockIdx.x;
  const int bk = id & 7;                   // b*KVH + kvh  (== XCD id under %8 rr)
  const int u = id >> 3;                   // 0..127
  const int jq = 127 - u;                  // descending work order
  const int b = bk >> 2, kvh = bk & 3;
  const int w = threadIdx.x >> 6;          // wave = q-head within group
  const int h = (kvh << 2) | w;
  const int lane = threadIdx.x & 63;
  const int colL = lane & 15, quad = lane >> 4;
  const int myq0 = jq * 16;                // 16 q-rows per block
  const int nkv = (jq >> 1) + 1;           // 32-row kv tiles covering causal range

  const bf16* kpt = kp + ((size_t)(bk * 64)) * 4096 + (w * 2) * 512 + lane * 8;
  const bf16* vpt = vp + ((size_t)(bk * 64)) * 4096 + (w * 2) * 512 + lane * 8;

  auto stageK = [&](int tile) {
    const bf16* s = kpt + (size_t)tile * 4096;
    bf16* d = &KS[tile & 1][(w * 2) * 512]; // wave-uniform base; HW adds lane*16B
    gload_lds16(s, d);
    gload_lds16(s + 512, d + 512);
  };
  auto stageV = [&](int tile) {
    const bf16* s = vpt + (size_t)tile * 4096;
    bf16* d = &VS[tile % 3][(w * 2) * 512];
    gload_lds16(s, d);
    gload_lds16(s + 512, d + 512);
  };

  // Q fragments (B-operand of K·Q^T), RoPE'd in registers.
  bf16x8 qf[4];
  {
    const bf16* qg = qkv + (size_t)(b * T_ + myq0) * NQKV + h * HD_;
    bf16x8 rq[4];
#pragma unroll
    for (int c = 0; c < 4; ++c)
      rq[c] = *(const bf16x8*)(qg + (size_t)colL * NQKV + c * 32 + quad * 8);
    const float2* tp = tab + (myq0 + colL) * 64 + quad * 8;
    float2 cs0[8], cs1[8];
#pragma unroll
    for (int jj = 0; jj < 8; ++jj) { cs0[jj] = tp[jj]; cs1[jj] = tp[32 + jj]; }
#pragma unroll
    for (int c = 0; c < 4; ++c) {
#pragma unroll
      for (int jj = 0; jj < 8; ++jj) {
        const float2 cs = (c & 1) ? cs1[jj] : cs0[jj];
        const float a = bfh2f(rq[c][jj]), p = bfh2f(rq[c ^ 2][jj]);
        qf[c][jj] = f2bf((c & 2) ? (a * cs.x + p * cs.y)
                                 : (a * cs.x - p * cs.y));
      }
    }
  }

  const f32x4 zero = {0.f, 0.f, 0.f, 0.f};
  auto qk = [&](const bf16* Kb, f32x4 (&s_)[2]) {
    s_[0] = zero; s_[1] = zero;
#pragma unroll
    for (int c = 0; c < 4; ++c) {
      bf16x8 kf0 = *(const bf16x8*)(Kb + c * 512 + lane * 8);
      bf16x8 kf1 = *(const bf16x8*)(Kb + (4 + c) * 512 + lane * 8);
      s_[0] = mfma32k(kf0, qf[c], s_[0]);
      s_[1] = mfma32k(kf1, qf[c], s_[1]);
    }
  };

  f32x4 o[8];
#pragma unroll
  for (int ht = 0; ht < 8; ++ht) o[ht] = zero;
  float l_ = 0.f;

  // prologue: K tiles 0,1 and V tiles 0,1; full drain; QK(0); publish barrier
  stageK(0);
  if (nkv > 1) stageK(1);
  stageV(0);
  if (nkv > 1) stageV(1);
  asm volatile("s_waitcnt vmcnt(0)\n\ts_barrier" ::: "memory");

  f32x4 sA[2], sB[2];
  qk(KS[0], sA);
  __builtin_amdgcn_s_barrier();            // slot-0 reads done before iter-0 stage

#pragma unroll 1
  for (int tt = 0; tt < nkv; ++tt) {
    const bool st = (tt + 2 < nkv);
    if (st) { stageV(tt + 2); stageK(tt + 2); }   // dist-2 prefetch (4 gloads)

    // QK(t+1): MFMA pipe busy while VALU does softmax(t)
    if (tt + 1 < nkv) qk(KS[(tt + 1) & 1], sB);

    // softmax on sA (tile tt); key-in-frame = quad*8 + kt*4 + i (r4 mapping)
    bf16x4 pf[2];
    if (tt == nkv - 1) {
      const int qg = ((jq & 1) << 4) | colL;   // q offset within 32-row kv frame
#pragma unroll
      for (int kt = 0; kt < 2; ++kt) {
        const int kb = quad * 8 + kt * 4;
        float pv[4];
#pragma unroll
        for (int i = 0; i < 4; ++i) {
          float e = fexp2(fmaf(sA[kt][i], FA_SCL2, -FA_M2));
          pv[i] = (kb + i <= qg) ? e : 0.f;
        }
        l_ += (pv[0] + pv[1]) + (pv[2] + pv[3]);
        pf[kt] = (bf16x4){f2bf(pv[0]), f2bf(pv[1]), f2bf(pv[2]), f2bf(pv[3])};
      }
    } else {
#pragma unroll
      for (int kt = 0; kt < 2; ++kt) {
        float pv[4];
#pragma unroll
        for (int i = 0; i < 4; ++i)
          pv[i] = fexp2(fmaf(sA[kt][i], FA_SCL2, -FA_M2));
        l_ += (pv[0] + pv[1]) + (pv[2] + pv[3]);
        pf[kt] = (bf16x4){f2bf(pv[0]), f2bf(pv[1]), f2bf(pv[2]), f2bf(pv[3])};
      }
    }

    // PV(tt): O^T += V^T · P^T — single K=32 MFMA per ht
    {
      const bf16* Vb = VS[tt % 3];
      const bf16x8 pcat = __builtin_shufflevector(pf[0], pf[1], 0, 1, 2, 3, 4, 5, 6, 7);
#pragma unroll
      for (int ht = 0; ht < 8; ++ht) {
        bf16x8 vf8 = *(const bf16x8*)(Vb + ht * 512 + lane * 8);
        o[ht] = mfma32k(vf8, pcat, o[ht]);
      }
    }

    // counted wait: drain K(tt+1),V(tt+1) (issued at tt-1 — latency covered);
    // leave this iter's 4 prefetches in flight. Tail: full drain.
    if (st) asm volatile("s_waitcnt vmcnt(4)\n\ts_barrier" ::: "memory");
    else    asm volatile("s_waitcnt vmcnt(0)\n\ts_barrier" ::: "memory");

    sA[0] = sB[0]; sA[1] = sB[1];
  }

  // epilogue: reduce l over key-quads, scale, direct store
  {
    float lv = l_;
    lv += __shfl_xor(lv, 16);
    lv += __shfl_xor(lv, 32);
    const float rl = 1.f / lv;
    const size_t rbase = (size_t)(b * T_ + myq0 + colL) * (H_ * HD_) + h * HD_;
#pragma unroll
    for (int ht = 0; ht < 8; ++ht) {
      bf16x4 ov;
#pragma unroll
      for (int i = 0; i < 4; ++i) ov[i] = f2bf(o[ht][i] * rl);
      *(bf16x4*)(ao + rbase + ht * 16 + quad * 4) = ov;
    }
  }
}

// ---------------------------------------------------------------------------
extern "C" void kernel_launch(void* const* d_in, const int* in_sizes, int n_in,
                              void* d_out, int out_size, void* d_ws, size_t ws_size,
                              hipStream_t stream) {
  (void)in_sizes; (void)n_in; (void)out_size; (void)ws_size;
  const float* x  = (const float*)d_in[0];
  const float* wq = (const float*)d_in[1];
  const float* bq = (const float*)d_in[2];
  const float* wk = (const float*)d_in[3];
  const float* bk = (const float*)d_in[4];
  const float* wv = (const float*)d_in[5];
  const float* bv = (const float*)d_in[6];
  const float* wo = (const float*)d_in[7];
  float* out = (float*)d_out;

  char* ws = (char*)d_ws;
  bf16* xb    = (bf16*)ws;                 // 16 MiB; reused as ao after QKV gemm
  bf16* wqkvT = (bf16*)(ws + (16u << 20)); // 12 MiB [3072][2048]
  bf16* woT   = (bf16*)(ws + (28u << 20)); //  8 MiB [2048][2048]
  bf16* qkv   = (bf16*)(ws + (36u << 20)); // 24 MiB [4096][3072] (Q cols only)
  bf16* kp    = (bf16*)(ws + (60u << 20)); //  8 MiB fragment-major roped K'
  bf16* vp    = (bf16*)(ws + (68u << 20)); //  8 MiB fragment-major V'
  float2* tab = (float2*)(ws + (76u << 20)); // 1 MiB RoPE cos/sin [2048][64]

  // 1: all independent prep (cast, weight transposes, rope table)
  prep_kernel<<<dim3(18944), dim3(256), 0, stream>>>(
      x, xb, wq, wk, wv, wqkvT, wo, woT, tab);

  // 2: fused QKV projection + K rope+pack / V pack in epilogue
  gemm_mfma64<true, true><<<dim3(NQKV / 128, MROWS / 128), dim3(256), 0, stream>>>(
      xb, wqkvT, qkv, bq, bk, bv, MROWS, NQKV, C_, kp, vp, tab);

  // 3: flash attention (Q roped in registers, dist-2 K/V prefetch, 4 blk/CU)
  bf16* ao = xb;
  flash_mfma8<<<dim3(1024), dim3(256), 0, stream>>>(qkv, kp, vp, ao, tab);

  // 4: output projection (m97 structure, BK=64 + swizzle)
  gemm_mfma64<false, false><<<dim3(C_ / 128, MROWS / 128), dim3(256), 0, stream>>>(
      ao, woT, out, nullptr, nullptr, nullptr, MROWS, C_, KOFF,
      nullptr, nullptr, nullptr);
}

// Round 11
// 289.914 us; speedup vs baseline: 1.0532x; 1.0114x over previous
//
#include <hip/hip_runtime.h>
#include <hip/hip_bf16.h>
#include <math.h>

#define B_ 2
#define T_ 2048
#define C_ 2048
#define H_ 16
#define KVH_ 4
#define HD_ 128
#define G_ (H_ / KVH_)
#define MROWS (B_ * T_)                    // 4096
#define NQKV (H_ * HD_ + 2 * KVH_ * HD_)   // 3072
#define KOFF (H_ * HD_)                    // 2048
#define VOFF (H_ * HD_ + KVH_ * HD_)       // 2560
#define L2T (13.287712379549449f / 64.0f)  // log2(10000)/64

typedef __hip_bfloat16 bf16;
typedef short bf16x8 __attribute__((ext_vector_type(8)));   // 8 bf16 = 4 VGPR
typedef short bf16x4 __attribute__((ext_vector_type(4)));   // 4 bf16 = 2 VGPR
typedef float f32x4 __attribute__((ext_vector_type(4)));

__device__ __forceinline__ void gload_lds16(const void* g, void* l) {
  __builtin_amdgcn_global_load_lds(
      (const __attribute__((address_space(1))) unsigned int*)g,
      (__attribute__((address_space(3))) unsigned int*)l, 16, 0, 0);
}

static __device__ __forceinline__ f32x4 mfma32k(bf16x8 a, bf16x8 b, f32x4 c) {
  return __builtin_amdgcn_mfma_f32_16x16x32_bf16(a, b, c, 0, 0, 0);
}

// fast RNE f32->bf16 (no NaN handling; inputs are finite)
static __device__ __forceinline__ short f2bf(float x) {
  unsigned u = __builtin_bit_cast(unsigned, x);
  u += 0x7FFFu + ((u >> 16) & 1u);
  return (short)(u >> 16);
}

// bf16 (raw short) -> f32
static __device__ __forceinline__ float bfh2f(short h) {
  unsigned u = ((unsigned)(unsigned short)h) << 16;
  return __builtin_bit_cast(float, u);
}

static __device__ __forceinline__ float fexp2(float x) {
#if __has_builtin(__builtin_amdgcn_exp2f)
  return __builtin_amdgcn_exp2f(x);
#else
  return exp2f(x);
#endif
}

// ---------------------------------------------------------------------------
// Fused prep: [0,8192)   cast x fp32->bf16
//             [8192,14336)  wq|wk|wv transpose-cast -> wqkvT [3072][2048]
//             [14336,18432) wo transpose-cast -> woT [2048][2048]
//             [18432,18944) RoPE cos/sin table [2048][64] float2
// ---------------------------------------------------------------------------
__global__ __launch_bounds__(256) void prep_kernel(
    const float* __restrict__ x, bf16* __restrict__ xb,
    const float* __restrict__ wq, const float* __restrict__ wk,
    const float* __restrict__ wv, bf16* __restrict__ wqkvT,
    const float* __restrict__ wo, bf16* __restrict__ woT,
    float2* __restrict__ tab) {
  __shared__ float t[32][33];
  int bid = blockIdx.x;
  if (bid < 8192) {                        // ---- cast x
    const int i = (bid * 256 + threadIdx.x) * 4;
    float4 v = *(const float4*)(x + i);
    xb[i + 0] = __float2bfloat16(v.x);
    xb[i + 1] = __float2bfloat16(v.y);
    xb[i + 2] = __float2bfloat16(v.z);
    xb[i + 3] = __float2bfloat16(v.w);
    return;
  }
  bid -= 8192;
  if (bid < 6144) {                        // ---- qkv weight transpose
    const int tx = threadIdx.x & 31, ty = threadIdx.x >> 5;
    const int c0 = (bid % 96) * 32;        // fused n-dim 0..3071
    const int r0 = (bid / 96) * 32;        // k-dim
    const float* src;
    int nn, ld;
    if (c0 < KOFF)      { src = wq; nn = c0;        ld = 2048; }
    else if (c0 < VOFF) { src = wk; nn = c0 - KOFF; ld = 512; }
    else                { src = wv; nn = c0 - VOFF; ld = 512; }
#pragma unroll
    for (int it = 0; it < 4; ++it)
      t[ty + 8 * it][tx] = src[(size_t)(r0 + ty + 8 * it) * ld + nn + tx];
    __syncthreads();
#pragma unroll
    for (int it = 0; it < 4; ++it)
      wqkvT[(size_t)(c0 + ty + 8 * it) * 2048 + r0 + tx] =
          __float2bfloat16(t[tx][ty + 8 * it]);
    return;
  }
  bid -= 6144;
  if (bid < 4096) {                        // ---- wo transpose
    const int tx = threadIdx.x & 31, ty = threadIdx.x >> 5;
    const int c0 = (bid & 63) * 32;
    const int r0 = (bid >> 6) * 32;
#pragma unroll
    for (int it = 0; it < 4; ++it)
      t[ty + 8 * it][tx] = wo[(size_t)(r0 + ty + 8 * it) * 2048 + c0 + tx];
    __syncthreads();
#pragma unroll
    for (int it = 0; it < 4; ++it)
      woT[(size_t)(c0 + ty + 8 * it) * 2048 + r0 + tx] =
          __float2bfloat16(t[tx][ty + 8 * it]);
    return;
  }
  bid -= 4096;
  {                                        // ---- RoPE table
    const int idx = bid * 256 + threadIdx.x;   // [0, 131072)
    const int tt = idx >> 6, i = idx & 63;
    const float invf = fexp2(-(float)i * L2T);
    float s, c;
    __sincosf((float)tt * invf, &s, &c);
    tab[idx] = make_float2(c, s);
  }
}

// ---------------------------------------------------------------------------
// bf16 MFMA GEMM, m97 loop structure with BK=64 + XOR swizzle (r7), plus
// FUSED K/V rope+pack epilogue (r8) for the QKV projection.
// Main loop identical to r7 (verified): 128x128 tile, 4 waves, BK=64,
// 2 barriers/tile; LDS rows 128B with 16B-slot XOR swizzle row&7 on both
// sides (pre-swizzled gload source / swizzled ds_read).
// FUSE epilogue (QKV only, blocks with c0 >= KOFF): the 128x128 output tile
// is exactly one kv head x 4 kv-tiles (blocks are head-aligned).
//   1) sync; dump bias-added acc as bf16 into the (dead) 32KB staging LDS as
//      T[128][128], col XOR-swizzled with (row&7)<<3;
//   2) barrier; each thread emits 8 x 16B units in the r4-verified kp/vp
//      fragment-major layouts; K gets table-RoPE in f32 (single rounding).
// Q blocks (c0 < KOFF) write qkv rows as before (flash reads only Q cols).
// ---------------------------------------------------------------------------
template <bool BF16OUT, bool FUSE>
__global__ __launch_bounds__(256, 2) void gemm_mfma64(
    const bf16* __restrict__ A, const bf16* __restrict__ Bt, void* __restrict__ Cout,
    const float* __restrict__ bq, const float* __restrict__ bk2,
    const float* __restrict__ bv2, int M, int N, int K,
    bf16* __restrict__ kp, bf16* __restrict__ vp, const float2* __restrict__ tab) {
  __shared__ __align__(16) short SH[2 * 128 * 64];  // As | Bs; FUSE: C-tile 128x128
  short* As = SH;
  short* Bs = SH + 128 * 64;
  const int tid = threadIdx.x;
  const int w = tid >> 6, lane = tid & 63;
  const int colL = lane & 15, quad = lane >> 4;
  const int wm = w & 1, wn = w >> 1;
  const int r0 = blockIdx.y * 128, c0 = blockIdx.x * 128;
  const int lrow = lane >> 3;                 // src row within 8-row seg
  const int lsl = ((lane & 7) ^ lrow) * 8;    // pre-swizzled src k-elems
  const int c7 = colL & 7;
  const int sq0 = (quad ^ c7) * 8;            // read slot (elems), ks=0
  const int sq1 = ((4 + quad) ^ c7) * 8;      // ks=1

  f32x4 acc[4][4];
  const f32x4 zero = {0.f, 0.f, 0.f, 0.f};
#pragma unroll
  for (int mt = 0; mt < 4; ++mt)
#pragma unroll
    for (int nt = 0; nt < 4; ++nt) acc[mt][nt] = zero;

  const bf16* pa = A + (size_t)(r0 + lrow) * K + lsl;
  const bf16* pb = Bt + (size_t)(c0 + lrow) * K + lsl;

  for (int k0 = 0; k0 < K; k0 += 64) {
    __syncthreads();                       // WAR: prev reads done (drains vmcnt too)
#pragma unroll
    for (int it = 0; it < 4; ++it) {
      const int seg = it * 4 + w;          // 16 segs x 8 rows x 128B
      gload_lds16(pa + (size_t)seg * 8 * K + k0, &As[seg * 8 * 64]);
      gload_lds16(pb + (size_t)seg * 8 * K + k0, &Bs[seg * 8 * 64]);
    }
    __syncthreads();                       // RAW: staging complete
#pragma unroll
    for (int ks = 0; ks < 2; ++ks) {
      const int sq = ks ? sq1 : sq0;
      bf16x8 af[4], bfv[4];
#pragma unroll
      for (int mt = 0; mt < 4; ++mt)
        af[mt] = *(const bf16x8*)&As[(wm * 64 + mt * 16 + colL) * 64 + sq];
#pragma unroll
      for (int nt = 0; nt < 4; ++nt)
        bfv[nt] = *(const bf16x8*)&Bs[(wn * 64 + nt * 16 + colL) * 64 + sq];
#pragma unroll
      for (int mt = 0; mt < 4; ++mt)
#pragma unroll
        for (int nt = 0; nt < 4; ++nt)
          acc[mt][nt] = mfma32k(af[mt], bfv[nt], acc[mt][nt]);
    }
  }

  if (!FUSE || c0 < KOFF) {
    // ---- plain epilogue: (bias +) store to Cout
#pragma unroll
    for (int nt = 0; nt < 4; ++nt) {
      const int c = c0 + wn * 64 + nt * 16 + colL;
      float bias = 0.f;
      if (bq) bias = (c < KOFF) ? bq[c] : (c < VOFF ? bk2[c - KOFF] : bv2[c - VOFF]);
#pragma unroll
      for (int mt = 0; mt < 4; ++mt) {
#pragma unroll
        for (int i = 0; i < 4; ++i) {
          const int r = r0 + wm * 64 + mt * 16 + quad * 4 + i;
          const float v = acc[mt][nt][i] + bias;
          if (BF16OUT)
            ((bf16*)Cout)[(size_t)r * N + c] = __float2bfloat16(v);
          else
            ((float*)Cout)[(size_t)r * N + c] = v;
        }
      }
    }
  } else {
    // ---- fused K/V rope+pack epilogue
    __syncthreads();                       // all As/Bs fragment reads complete
    const bool isK = (c0 < VOFF);
#pragma unroll
    for (int nt = 0; nt < 4; ++nt) {
      const int c = c0 + wn * 64 + nt * 16 + colL;
      const float bias = isK ? bk2[c - KOFF] : bv2[c - VOFF];
      const int col = wn * 64 + nt * 16 + colL;
#pragma unroll
      for (int mt = 0; mt < 4; ++mt) {
#pragma unroll
        for (int i = 0; i < 4; ++i) {
          const int row = wm * 64 + mt * 16 + quad * 4 + i;
          SH[row * 128 + (col ^ ((row & 7) << 3))] = f2bf(acc[mt][nt][i] + bias);
        }
      }
    }
    __syncthreads();
    const int b = r0 >> 11;                         // batch
    const int tbase = (r0 & 2047) >> 5;             // first 32-row kv tile
    const int kvh = (c0 - (isK ? KOFF : VOFF)) >> 7;
    const int bkq = b * 4 + kvh;
    if (isK) {
#pragma unroll
      for (int s = 0; s < 8; ++s) {
        const int unit = s * 256 + tid;             // 2048 16B-units
        const int L = unit & 63, kc = (unit >> 6) & 7, tile = unit >> 9;
        const int trow = tile * 32 + ((L >> 2) & 3) * 8 + ((kc >> 2) << 2) + (L & 3);
        const int d = (kc & 3) * 32 + ((L >> 4) << 3);
        const int sx = (trow & 7) << 3;
        bf16x8 lo = *(const bf16x8*)&SH[trow * 128 + (d ^ sx)];
        bf16x8 hi = *(const bf16x8*)&SH[trow * 128 + ((d ^ 64) ^ sx)];
        const int t_abs = (r0 + trow) & (T_ - 1);
        const float2* tp = tab + t_abs * 64 + (d & 63);
        bf16x8 outv;
#pragma unroll
        for (int j = 0; j < 8; ++j) {
          const float2 cs = tp[j];
          const float a = bfh2f(lo[j]), p = bfh2f(hi[j]);
          outv[j] = f2bf((d < 64) ? (a * cs.x - p * cs.y) : (a * cs.x + p * cs.y));
        }
        *(bf16x8*)(kp + ((size_t)((bkq * 64 + tbase + tile) * 8 + kc)) * 512 + L * 8) = outv;
      }
    } else {
#pragma unroll
      for (int s = 0; s < 8; ++s) {
        const int unit = s * 256 + tid;
        const int L = unit & 63, ht = (unit >> 6) & 7, tile = unit >> 9;
        const int rowb = tile * 32 + ((L >> 4) << 3);
        const int colv = ht * 16 + (L & 15);
        bf16x8 v;
#pragma unroll
        for (int j = 0; j < 8; ++j)
          v[j] = SH[(rowb + j) * 128 + (colv ^ (((rowb + j) & 7) << 3))];
        *(bf16x8*)(vp + ((size_t)((bkq * 64 + tbase + tile) * 8 + ht)) * 512 + L * 8) = v;
      }
    }
  }
}

// ---------------------------------------------------------------------------
// Causal GQA flash attention v17: V in REGISTERS via PINNED asm global loads.
// Pipe arithmetic (r10): per block-iter the 4 waves issued 64 ds_read_b128
// (~768 CU-cyc of LDS pipe) against 1385 measured cyc — LDS was the largest
// pipe consumer. V reads were 4x-redundant (all waves read the same tile).
// Fix: V never enters LDS. Each wave loads the full 8KB V tile to registers
// with 8 x `asm volatile global_load_dwordx4` at iteration TOP — volatile asm
// is not sinkable (r9's failure was the compiler sinking intrinsic-free loads
// to first use). L2 latency hides under qk+softmax. LDS traffic per iter
// halves (8 K ds_reads only); gload_lds V staging gone.
// Sync ledger (FIFO-walked nkv=1,2,3,steady,tail): iter tt issues V8(tt) then
// K2(tt+3) [3-slot dist-3 K, slot=tile%3 — dist-2 breaks: K(tt+1) would
// still be in flight at qk(tt+1)]. Pre-PV PER-WAVE wait vmcnt(2) (vmcnt(0)
// on tail) drains K(tt+2)+V(tt), leaves K(tt+3); sched_barrier(0) after it
// (rule #18: MFMA reading asm-loaded VGPRs can hoist past asm waitcnt).
// End-of-iter barrier is BARE (no vmcnt): each wave's own pre-PV wait already
// drained its chunks of K(tt+2); barrier orders slot reuse (stage of slot s
// at iter tt+1 vs qk reads of slot s at iter tt). Post-prologue barrier
// closes the slot-0 WAR (iter-0 stageK(3)->slot0 vs prologue qk(0) reads).
// LDS 40->24KB. VGPR ~110 (vr 32 + o 32 + qf 16 + pipeline) cap 128 @ 4/CU.
// Everything else = r6/r8 proven: 16-row q-tiles, 1024 blocks, jq=127-u,
// in-register Q RoPE, PV single K=32 MFMA per ht, fixed-max softmax (exact).
// ---------------------------------------------------------------------------
#define FA_SCL2 (0.08838834764831845f * 1.4426950408889634f)  // scale * log2(e)
#define FA_M2 16.0f                                           // fixed max (exp2 domain)

__global__ __launch_bounds__(256, 4) void flash_mfma8(
    const bf16* __restrict__ qkv, const bf16* __restrict__ kp,
    const bf16* __restrict__ vp, bf16* __restrict__ ao,
    const float2* __restrict__ tab) {
  __shared__ __align__(16) bf16 KS[3][4096];   // 3 x 8KB, dist 3 (V is reg-only)

  const int id = blockIdx.x;
  const int bk = id & 7;                   // b*KVH + kvh  (== XCD id under %8 rr)
  const int u = id >> 3;                   // 0..127
  const int jq = 127 - u;                  // descending work order
  const int b = bk >> 2, kvh = bk & 3;
  const int w = threadIdx.x >> 6;          // wave = q-head within group
  const int h = (kvh << 2) | w;
  const int lane = threadIdx.x & 63;
  const int colL = lane & 15, quad = lane >> 4;
  const int myq0 = jq * 16;                // 16 q-rows per block
  const int nkv = (jq >> 1) + 1;           // 32-row kv tiles covering causal range

  const bf16* kpt = kp + ((size_t)(bk * 64)) * 4096 + (w * 2) * 512 + lane * 8;
  const bf16* vbase = vp + ((size_t)(bk * 64)) * 4096 + lane * 8;

  auto stageK = [&](int tile) {
    const bf16* s = kpt + (size_t)tile * 4096;
    bf16* d = &KS[tile % 3][(w * 2) * 512]; // wave-uniform base; HW adds lane*16B
    gload_lds16(s, d);
    gload_lds16(s + 512, d + 512);
  };

  // Q fragments (B-operand of K·Q^T), RoPE'd in registers.
  bf16x8 qf[4];
  {
    const bf16* qg = qkv + (size_t)(b * T_ + myq0) * NQKV + h * HD_;
    bf16x8 rq[4];
#pragma unroll
    for (int c = 0; c < 4; ++c)
      rq[c] = *(const bf16x8*)(qg + (size_t)colL * NQKV + c * 32 + quad * 8);
    const float2* tp = tab + (myq0 + colL) * 64 + quad * 8;
    float2 cs0[8], cs1[8];
#pragma unroll
    for (int jj = 0; jj < 8; ++jj) { cs0[jj] = tp[jj]; cs1[jj] = tp[32 + jj]; }
#pragma unroll
    for (int c = 0; c < 4; ++c) {
#pragma unroll
      for (int jj = 0; jj < 8; ++jj) {
        const float2 cs = (c & 1) ? cs1[jj] : cs0[jj];
        const float a = bfh2f(rq[c][jj]), p = bfh2f(rq[c ^ 2][jj]);
        qf[c][jj] = f2bf((c & 2) ? (a * cs.x + p * cs.y)
                                 : (a * cs.x - p * cs.y));
      }
    }
  }

  const f32x4 zero = {0.f, 0.f, 0.f, 0.f};
  auto qk = [&](const bf16* Kb, f32x4 (&s_)[2]) {
    s_[0] = zero; s_[1] = zero;
#pragma unroll
    for (int c = 0; c < 4; ++c) {
      bf16x8 kf0 = *(const bf16x8*)(Kb + c * 512 + lane * 8);
      bf16x8 kf1 = *(const bf16x8*)(Kb + (4 + c) * 512 + lane * 8);
      s_[0] = mfma32k(kf0, qf[c], s_[0]);
      s_[1] = mfma32k(kf1, qf[c], s_[1]);
    }
  };

  f32x4 o[8];
#pragma unroll
  for (int ht = 0; ht < 8; ++ht) o[ht] = zero;
  float l_ = 0.f;

  // prologue: K tiles 0..2 into LDS; full drain; QK(0); slot-publish barrier
  stageK(0);
  if (nkv > 1) stageK(1);
  if (nkv > 2) stageK(2);
  asm volatile("s_waitcnt vmcnt(0)\n\ts_barrier" ::: "memory");

  f32x4 sA[2], sB[2];
  qk(KS[0], sA);
  __builtin_amdgcn_s_barrier();            // slot-0 reads done before iter-0 stageK(3)

#pragma unroll 1
  for (int tt = 0; tt < nkv; ++tt) {
    const bool sk = (tt + 3 < nkv);

    // V(tt) global->reg, issue PINNED at iteration top (volatile asm)
    bf16x8 vr[8];
    {
      const bf16* v0 = vbase + (size_t)tt * 4096;
      const bf16* v1 = v0 + 2048;
      asm volatile("global_load_dwordx4 %0, %1, off"             : "=v"(vr[0]) : "v"(v0));
      asm volatile("global_load_dwordx4 %0, %1, off offset:1024" : "=v"(vr[1]) : "v"(v0));
      asm volatile("global_load_dwordx4 %0, %1, off offset:2048" : "=v"(vr[2]) : "v"(v0));
      asm volatile("global_load_dwordx4 %0, %1, off offset:3072" : "=v"(vr[3]) : "v"(v0));
      asm volatile("global_load_dwordx4 %0, %1, off"             : "=v"(vr[4]) : "v"(v1));
      asm volatile("global_load_dwordx4 %0, %1, off offset:1024" : "=v"(vr[5]) : "v"(v1));
      asm volatile("global_load_dwordx4 %0, %1, off offset:2048" : "=v"(vr[6]) : "v"(v1));
      asm volatile("global_load_dwordx4 %0, %1, off offset:3072" : "=v"(vr[7]) : "v"(v1));
    }
    if (sk) stageK(tt + 3);                // 2 gload_lds, newest in FIFO

    // QK(t+1): MFMA pipe busy while VALU does softmax(t)
    if (tt + 1 < nkv) qk(KS[(tt + 1) % 3], sB);

    // softmax on sA (tile tt); key-in-frame = quad*8 + kt*4 + i (r4 mapping)
    bf16x4 pf[2];
    if (tt == nkv - 1) {
      const int qg = ((jq & 1) << 4) | colL;   // q offset within 32-row kv frame
#pragma unroll
      for (int kt = 0; kt < 2; ++kt) {
        const int kb = quad * 8 + kt * 4;
        float pv[4];
#pragma unroll
        for (int i = 0; i < 4; ++i) {
          float e = fexp2(fmaf(sA[kt][i], FA_SCL2, -FA_M2));
          pv[i] = (kb + i <= qg) ? e : 0.f;
        }
        l_ += (pv[0] + pv[1]) + (pv[2] + pv[3]);
        pf[kt] = (bf16x4){f2bf(pv[0]), f2bf(pv[1]), f2bf(pv[2]), f2bf(pv[3])};
      }
    } else {
#pragma unroll
      for (int kt = 0; kt < 2; ++kt) {
        float pv[4];
#pragma unroll
        for (int i = 0; i < 4; ++i)
          pv[i] = fexp2(fmaf(sA[kt][i], FA_SCL2, -FA_M2));
        l_ += (pv[0] + pv[1]) + (pv[2] + pv[3]);
        pf[kt] = (bf16x4){f2bf(pv[0]), f2bf(pv[1]), f2bf(pv[2]), f2bf(pv[3])};
      }
    }

    // per-wave counted wait: drain V(tt) [+K(tt+2) from last iter], leave
    // K(tt+3) in flight; sched_barrier stops MFMA hoisting past it (rule 18)
    if (sk) asm volatile("s_waitcnt vmcnt(2)" ::: "memory");
    else    asm volatile("s_waitcnt vmcnt(0)" ::: "memory");
    __builtin_amdgcn_sched_barrier(0);

    // PV(tt): O^T += V^T · P^T — single K=32 MFMA per ht, V from registers
    {
      const bf16x8 pcat = __builtin_shufflevector(pf[0], pf[1], 0, 1, 2, 3, 4, 5, 6, 7);
#pragma unroll
      for (int ht = 0; ht < 8; ++ht)
        o[ht] = mfma32k(vr[ht], pcat, o[ht]);
    }

    // bare barrier: orders K slot reuse (stage at iter tt+1 vs reads at tt);
    // all cross-wave data deps already published via per-wave pre-PV waits
    __builtin_amdgcn_s_barrier();

    sA[0] = sB[0]; sA[1] = sB[1];
  }

  // epilogue: reduce l over key-quads, scale, direct store
  {
    float lv = l_;
    lv += __shfl_xor(lv, 16);
    lv += __shfl_xor(lv, 32);
    const float rl = 1.f / lv;
    const size_t rbase = (size_t)(b * T_ + myq0 + colL) * (H_ * HD_) + h * HD_;
#pragma unroll
    for (int ht = 0; ht < 8; ++ht) {
      bf16x4 ov;
#pragma unroll
      for (int i = 0; i < 4; ++i) ov[i] = f2bf(o[ht][i] * rl);
      *(bf16x4*)(ao + rbase + ht * 16 + quad * 4) = ov;
    }
  }
}

// ---------------------------------------------------------------------------
extern "C" void kernel_launch(void* const* d_in, const int* in_sizes, int n_in,
                              void* d_out, int out_size, void* d_ws, size_t ws_size,
                              hipStream_t stream) {
  (void)in_sizes; (void)n_in; (void)out_size; (void)ws_size;
  const float* x  = (const float*)d_in[0];
  const float* wq = (const float*)d_in[1];
  const float* bq = (const float*)d_in[2];
  const float* wk = (const float*)d_in[3];
  const float* bk = (const float*)d_in[4];
  const float* wv = (const float*)d_in[5];
  const float* bv = (const float*)d_in[6];
  const float* wo = (const float*)d_in[7];
  float* out = (float*)d_out;

  char* ws = (char*)d_ws;
  bf16* xb    = (bf16*)ws;                 // 16 MiB; reused as ao after QKV gemm
  bf16* wqkvT = (bf16*)(ws + (16u << 20)); // 12 MiB [3072][2048]
  bf16* woT   = (bf16*)(ws + (28u << 20)); //  8 MiB [2048][2048]
  bf16* qkv   = (bf16*)(ws + (36u << 20)); // 24 MiB [4096][3072] (Q cols only)
  bf16* kp    = (bf16*)(ws + (60u << 20)); //  8 MiB fragment-major roped K'
  bf16* vp    = (bf16*)(ws + (68u << 20)); //  8 MiB fragment-major V'
  float2* tab = (float2*)(ws + (76u << 20)); // 1 MiB RoPE cos/sin [2048][64]

  // 1: all independent prep (cast, weight transposes, rope table)
  prep_kernel<<<dim3(18944), dim3(256), 0, stream>>>(
      x, xb, wq, wk, wv, wqkvT, wo, woT, tab);

  // 2: fused QKV projection + K rope+pack / V pack in epilogue
  gemm_mfma64<true, true><<<dim3(NQKV / 128, MROWS / 128), dim3(256), 0, stream>>>(
      xb, wqkvT, qkv, bq, bk, bv, MROWS, NQKV, C_, kp, vp, tab);

  // 3: flash attention (Q roped in regs, V reg-loaded via pinned asm)
  bf16* ao = xb;
  flash_mfma8<<<dim3(1024), dim3(256), 0, stream>>>(qkv, kp, vp, ao, tab);

  // 4: output projection (m97 structure, BK=64 + swizzle)
  gemm_mfma64<false, false><<<dim3(C_ / 128, MROWS / 128), dim3(256), 0, stream>>>(
      ao, woT, out, nullptr, nullptr, nullptr, MROWS, C_, KOFF,
      nullptr, nullptr, nullptr);
}